// Round 13
// baseline (220.143 us; speedup 1.0000x reference)
//
#include <hip/hip_runtime.h>
#include <hip/hip_bf16.h>

#define NN 50000
#define EE 800000
#define HH 2
#define CC 64
#define CEE 32
#define NODE_BLOCKS ((NN + 63) / 64)
#define COUNT_BLOCKS ((EE + 255) / 256)

typedef __attribute__((ext_vector_type(8))) short bf16x8;
typedef __attribute__((ext_vector_type(4))) float f32x4;

__device__ __forceinline__ short f2bf(float f) {
    union { float f; unsigned u; } v; v.f = f;
    unsigned r = v.u + 0x7FFF + ((v.u >> 16) & 1);   // RNE
    return (short)(r >> 16);
}
__device__ __forceinline__ unsigned pack2(float a, float b) {
    return (unsigned)(unsigned short)f2bf(a) | ((unsigned)(unsigned short)f2bf(b) << 16);
}
__device__ __forceinline__ float bfh(unsigned u) { return __uint_as_float(u & 0xFFFF0000u); }
__device__ __forceinline__ float bfl(unsigned u) { return __uint_as_float(u << 16); }

// ---------------- K_prep (fused): b0 = Wc/bc combine, b1 = WlT bf16 transpose,
// b2..129 = projection WT rows
__global__ __launch_bounds__(512) void k_prep(const float* __restrict__ We,
                                              const float* __restrict__ be,
                                              const float* __restrict__ Weo,
                                              const float* __restrict__ beo,
                                              const float* __restrict__ Wl,
                                              const float* __restrict__ Wno,
                                              float* __restrict__ Wc,
                                              float* __restrict__ bc,
                                              unsigned short* __restrict__ WlT,
                                              unsigned short* __restrict__ WT) {
    int b = blockIdx.x, t = threadIdx.x;
    if (b == 0) {
        for (int i = t; i < 1024; i += 512) {
            int r = i >> 5, j = i & 31;
            float s = 0.f;
            #pragma unroll
            for (int k = 0; k < 64; k++) s += We[r * 64 + k] * Weo[k * 32 + j];
            Wc[i] = s;
        }
        if (t < 32) {
            float bsum = beo[t];
            #pragma unroll
            for (int k = 0; k < 64; k++) bsum += be[k] * Weo[k * 32 + t];
            bc[t] = bsum;
        }
    } else if (b == 1) {
        for (int i = t; i < 16384; i += 512) {
            int o = i >> 7, k = i & 127;
            WlT[o * 128 + k] = (unsigned short)f2bf(Wl[k * 128 + o]);
        }
    } else {
        int o = b - 2;         // 0..127
        int r = t;             // 0..511  (= h*256 + agg*64 + c)
        int h = r >> 8, q = r & 255;
        const float* base = Wno + (size_t)(h * 768 + q) * 64;
        float v;
        if (o < 64) v = base[o] + base[512 * 64 + o];
        else        v = base[256 * 64 + (o - 64)];
        WT[(size_t)o * 512 + r] = (unsigned short)f2bf(v);
    }
}

// ---------------- K1: MFMA bf16 GEMM xl = x @ W_l + b_l; fused ai/aj epilogue.
// Extra blocks (>= NODE_BLOCKS) do the degree count + rank assignment.
__global__ __launch_bounds__(256) void k_node3(const float* __restrict__ x,
                                               const unsigned short* __restrict__ WlT,
                                               const float* __restrict__ bl,
                                               const float* __restrict__ att,
                                               const int* __restrict__ ei,
                                               int* __restrict__ counts,
                                               int* __restrict__ rank,
                                               unsigned short* __restrict__ xl,
                                               float* __restrict__ ai,
                                               float* __restrict__ aj) {
    if ((int)blockIdx.x >= NODE_BLOCKS) {
        int e = ((int)blockIdx.x - NODE_BLOCKS) * 256 + threadIdx.x;
        if (e < EE) rank[e] = atomicAdd(&counts[ei[EE + e]], 1);
        return;
    }
    __shared__ unsigned short sX[64][40];    // 64 nodes x 32-k chunk bf16
    __shared__ unsigned short sW[128][40];   // 128 out-cols x 32-k chunk bf16
    int t = threadIdx.x;
    int lane = t & 63, wave = t >> 6;
    int l15 = lane & 15, lq = lane >> 4;
    int n0 = blockIdx.x * 64;

    f32x4 acc[8];
    #pragma unroll
    for (int cb = 0; cb < 8; cb++) acc[cb] = (f32x4){0.f, 0.f, 0.f, 0.f};

    int arow = t >> 2, achk = (t & 3) * 8;
    int an = n0 + arow; if (an >= NN) an = NN - 1;
    const float* Aptr = x + (size_t)an * 128 + achk;
    int bcol0 = t >> 2, bcol1 = (t + 256) >> 2, bchk = (t & 3) * 8;
    const unsigned short* Bp0 = WlT + (size_t)bcol0 * 128 + bchk;
    const unsigned short* Bp1 = WlT + (size_t)bcol1 * 128 + bchk;

    for (int kc = 0; kc < 128; kc += 32) {
        __syncthreads();
        float4 a0 = *(const float4*)(Aptr + kc);
        float4 a1 = *(const float4*)(Aptr + kc + 4);
        uint4 pk;
        pk.x = pack2(a0.x, a0.y); pk.y = pack2(a0.z, a0.w);
        pk.z = pack2(a1.x, a1.y); pk.w = pack2(a1.z, a1.w);
        *(uint4*)&sX[arow][achk] = pk;
        *(uint4*)&sW[bcol0][bchk] = *(const uint4*)(Bp0 + kc);
        *(uint4*)&sW[bcol1][bchk] = *(const uint4*)(Bp1 + kc);
        __syncthreads();
        bf16x8 afrag = *(const bf16x8*)&sX[wave * 16 + l15][lq * 8];
        #pragma unroll
        for (int cb = 0; cb < 8; cb++) {
            bf16x8 bfrag = *(const bf16x8*)&sW[cb * 16 + l15][lq * 8];
            acc[cb] = __builtin_amdgcn_mfma_f32_16x16x32_bf16(afrag, bfrag, acc[cb], 0, 0, 0);
        }
    }

    // epilogue: +bias, bf16 xl write, lrelu*att partials, l15-butterfly
    float blv[8], atti[8], attj[8];
    #pragma unroll
    for (int cb = 0; cb < 8; cb++) {
        int o = cb * 16 + l15;
        blv[cb] = bl[o];
        int h = o >> 6, c = o & 63;
        atti[cb] = att[h * 160 + c];
        attj[cb] = att[h * 160 + 64 + c];
    }
    int nodebase = n0 + wave * 16 + lq * 4;
    #pragma unroll
    for (int r = 0; r < 4; r++) {
        int node = nodebase + r;
        bool ok = node < NN;
        float s0a = 0.f, s1a = 0.f, s0j = 0.f, s1j = 0.f;
        #pragma unroll
        for (int cb = 0; cb < 8; cb++) {
            float v = acc[cb][r] + blv[cb];
            if (ok) xl[(size_t)node * 128 + cb * 16 + l15] = (unsigned short)f2bf(v);
            float lr = v > 0.f ? v : 0.2f * v;
            if (cb < 4) { s0a += lr * atti[cb]; s0j += lr * attj[cb]; }
            else        { s1a += lr * atti[cb]; s1j += lr * attj[cb]; }
        }
        #pragma unroll
        for (int m = 1; m <= 8; m <<= 1) {
            s0a += __shfl_xor(s0a, m); s1a += __shfl_xor(s1a, m);
            s0j += __shfl_xor(s0j, m); s1j += __shfl_xor(s1j, m);
        }
        if (l15 == 0 && ok) {
            *(float2*)(ai + (size_t)node * 2) = make_float2(s0a, s1a);
            *(float2*)(aj + (size_t)node * 2) = make_float2(s0j, s1j);
        }
    }
}

// ---------------- scan: block-local exclusive + bsums + avg_log
__global__ __launch_bounds__(1024) void k_scan1(const int* __restrict__ counts,
                                                int* __restrict__ offsets,
                                                int* __restrict__ bsums,
                                                float* __restrict__ avgsum) {
    __shared__ int s[1024];
    int g = blockIdx.x * 1024 + threadIdx.x;
    int v = (g < NN) ? counts[g] : 0;
    s[threadIdx.x] = v;
    __syncthreads();
    for (int st = 1; st < 1024; st <<= 1) {
        int t = (threadIdx.x >= st) ? s[threadIdx.x - st] : 0;
        __syncthreads();
        s[threadIdx.x] += t;
        __syncthreads();
    }
    if (g < NN) offsets[g] = s[threadIdx.x] - v;
    if (threadIdx.x == 1023) bsums[blockIdx.x] = s[1023];
    float lv = (g < NN) ? logf((float)v + 1.0f) : 0.0f;
    #pragma unroll
    for (int m = 32; m; m >>= 1) lv += __shfl_xor(lv, m);
    if ((threadIdx.x & 63) == 0) atomicAdd(avgsum, lv);
}

// scan2+scan3 fused: block base = sum(bsums[0..bid-1]) computed in-wave (nb<=64)
__global__ __launch_bounds__(1024) void k_scan23(int* __restrict__ offsets,
                                                 const int* __restrict__ bsums) {
    __shared__ int sbase;
    int t = threadIdx.x;
    if (t < 64) {
        int v = (t < (int)blockIdx.x) ? bsums[t] : 0;
        #pragma unroll
        for (int m = 32; m; m >>= 1) v += __shfl_xor(v, m);
        if (t == 0) sbase = v;
    }
    __syncthreads();
    int g = blockIdx.x * 1024 + t;
    if (g < NN) offsets[g] += sbase;
}

// ---------------- K3: MFMA edge pass; bias/att/bc constants moved to LDS
// (frees ~40 VGPRs of loop-invariant broadcast data -> target <=64 VGPR tier).
__global__ __launch_bounds__(256) void k_edge8(const float* __restrict__ ea,
                                               const int* __restrict__ ei,
                                               const float* __restrict__ We,
                                               const float* __restrict__ be,
                                               const float* __restrict__ att,
                                               const float* __restrict__ Wc,
                                               const float* __restrict__ bc,
                                               const float* __restrict__ ai,
                                               const float* __restrict__ aj,
                                               const int* __restrict__ offsets,
                                               const int* __restrict__ rank,
                                               float4* __restrict__ csr4,
                                               float* __restrict__ eout) {
    __shared__ float sbe[64], satt[64], sbc[32];
    int t = threadIdx.x;
    int lane = t & 63, wave = t >> 6;
    int l15 = lane & 15, lq = lane >> 4;
    int ew0 = blockIdx.x * 256 + wave * 64;

    if (t < 64) {
        sbe[t]  = be[t];
        satt[t] = att[(t >> 5) * 160 + 128 + (t & 31)];
    } else if (t < 96) {
        sbc[t - 64] = bc[t - 64];
    }

    // metadata first (longest dependent chain: dst -> offsets/ai)
    int myE = ew0 + lane;
    int msrc = ei[myE], mdst = ei[EE + myE];
    int myrank = rank[myE];
    int obase = offsets[mdst];
    float2 aiv = *(const float2*)(ai + (size_t)mdst * 2);
    float2 ajv = *(const float2*)(aj + (size_t)msrc * 2);

    // attr loads: 2-deep double buffer, convert to bf16 immediately
    bf16x8 bEall[4];
    {
        float4 fb0, fb1;
        {
            const float4* p = (const float4*)(ea + (size_t)(ew0 + l15) * 32 + lq * 8);
            fb0 = p[0]; fb1 = p[1];
        }
        #pragma unroll
        for (int g = 0; g < 4; g++) {
            float4 c0 = fb0, c1 = fb1;
            if (g < 3) {
                const float4* p = (const float4*)(ea + (size_t)(ew0 + (g + 1) * 16 + l15) * 32 + lq * 8);
                fb0 = p[0]; fb1 = p[1];
            }
            bf16x8 bE;
            bE[0] = f2bf(c0.x); bE[1] = f2bf(c0.y); bE[2] = f2bf(c0.z); bE[3] = f2bf(c0.w);
            bE[4] = f2bf(c1.x); bE[5] = f2bf(c1.y); bE[6] = f2bf(c1.z); bE[7] = f2bf(c1.w);
            bEall[g] = bE;
        }
    }

    bf16x8 aWe[4], aWc[2];
    #pragma unroll
    for (int mb = 0; mb < 4; mb++)
        #pragma unroll
        for (int j = 0; j < 8; j++)
            aWe[mb][j] = f2bf(We[(lq * 8 + j) * 64 + mb * 16 + l15]);
    #pragma unroll
    for (int cb = 0; cb < 2; cb++)
        #pragma unroll
        for (int j = 0; j < 8; j++)
            aWc[cb][j] = f2bf(Wc[(lq * 8 + j) * 32 + cb * 16 + l15]);

    __syncthreads();

    const f32x4 zc = (f32x4){0.f, 0.f, 0.f, 0.f};
    float myP0 = 0.f, myP1 = 0.f;

    #pragma unroll
    for (int g = 0; g < 4; g++) {
        int e = ew0 + g * 16 + l15;
        bf16x8 bE = bEall[g];

        float p0 = 0.f, p1 = 0.f;
        #pragma unroll
        for (int mb = 0; mb < 4; mb++) {
            f32x4 acc = __builtin_amdgcn_mfma_f32_16x16x32_bf16(aWe[mb], bE, zc, 0, 0, 0);
            float ps = 0.f;
            #pragma unroll
            for (int r = 0; r < 4; r++) {
                int midx = mb * 16 + lq * 4 + r;
                float m = acc[r] + sbe[midx];
                float lr = m > 0.f ? m : 0.2f * m;
                ps += lr * satt[midx];
            }
            if (mb < 2) p0 += ps; else p1 += ps;
        }
        p0 += __shfl_xor(p0, 16); p0 += __shfl_xor(p0, 32);
        p1 += __shfl_xor(p1, 16); p1 += __shfl_xor(p1, 32);
        if (lq == g) { myP0 = p0; myP1 = p1; }

        #pragma unroll
        for (int cb = 0; cb < 2; cb++) {
            f32x4 oc = __builtin_amdgcn_mfma_f32_16x16x32_bf16(aWc[cb], bE, zc, 0, 0, 0);
            int cidx = cb * 16 + lq * 4;
            *(float4*)(eout + (size_t)e * 32 + cidx) =
                make_float4(oc[0] + sbc[cidx], oc[1] + sbc[cidx + 1],
                            oc[2] + sbc[cidx + 2], oc[3] + sbc[cidx + 3]);
        }
    }

    float lg0 = myP0 + aiv.x + ajv.x;
    float lg1 = myP1 + aiv.y + ajv.y;
    csr4[obase + myrank] = make_float4(__int_as_float(msrc), lg0, lg1, 0.f);
}

// ---------------- K4: one wave per NODE, both heads fused; LDS-broadcast alphas
__global__ __launch_bounds__(256) void k_aggr2(const int* __restrict__ counts,
                                               const int* __restrict__ offsets,
                                               const float4* __restrict__ csr4,
                                               const unsigned short* __restrict__ xl,
                                               unsigned short* __restrict__ out_ws) {
    __shared__ float4 sal[4][64];   // per-wave {src, a0, a1, -} table (4 KB)
    int lane = threadIdx.x & 63;
    int wv = threadIdx.x >> 6;
    int n = blockIdx.x * 4 + wv;
    if (n >= NN) return;
    int deg = counts[n], start = offsets[n];

    float sum0 = 0.f, sum1 = 0.f, sq0 = 0.f, sq1 = 0.f;
    float mn0 = 1e30f, mn1 = 1e30f, mx0 = -1e30f, mx1 = -1e30f;

    if (deg > 0 && deg <= 64) {
        float2 lg = make_float2(-1e30f, -1e30f);
        int srcv = 0;
        if (lane < deg) {
            float4 c = csr4[start + lane];
            srcv = __float_as_int(c.x);
            lg = make_float2(c.y, c.z);
        }
        float m0 = lg.x, m1 = lg.y;
        #pragma unroll
        for (int s = 32; s; s >>= 1) {
            m0 = fmaxf(m0, __shfl_xor(m0, s));
            m1 = fmaxf(m1, __shfl_xor(m1, s));
        }
        float e0 = (lane < deg) ? __expf(lg.x - m0) : 0.f;
        float e1 = (lane < deg) ? __expf(lg.y - m1) : 0.f;
        float s0 = e0, s1 = e1;
        #pragma unroll
        for (int s = 32; s; s >>= 1) {
            s0 += __shfl_xor(s0, s);
            s1 += __shfl_xor(s1, s);
        }
        sal[wv][lane] = make_float4(__int_as_float(srcv),
                                    e0 / (s0 + 1e-16f), e1 / (s1 + 1e-16f), 0.f);
        #pragma unroll 4
        for (int i = 0; i < deg; i++) {
            float4 c = sal[wv][i];                 // broadcast read, conflict-free
            int sidx = __float_as_int(c.x);
            float alpha = (lane < 32) ? c.y : c.z;
            unsigned u = *(const unsigned*)(xl + (size_t)sidx * 128 + lane * 2);
            float g0 = bfl(u) * alpha, g1 = bfh(u) * alpha;
            sum0 += g0; sum1 += g1;
            sq0 += g0 * g0; sq1 += g1 * g1;
            mn0 = fminf(mn0, g0); mn1 = fminf(mn1, g1);
            mx0 = fmaxf(mx0, g0); mx1 = fmaxf(mx1, g1);
        }
    } else if (deg > 64) {
        float m0 = -1e30f, m1 = -1e30f;
        for (int i = lane; i < deg; i += 64) {
            float4 c = csr4[start + i];
            m0 = fmaxf(m0, c.y); m1 = fmaxf(m1, c.z);
        }
        #pragma unroll
        for (int s = 32; s; s >>= 1) {
            m0 = fmaxf(m0, __shfl_xor(m0, s));
            m1 = fmaxf(m1, __shfl_xor(m1, s));
        }
        float s0 = 0.f, s1 = 0.f;
        for (int i = lane; i < deg; i += 64) {
            float4 c = csr4[start + i];
            s0 += __expf(c.y - m0); s1 += __expf(c.z - m1);
        }
        #pragma unroll
        for (int s = 32; s; s >>= 1) {
            s0 += __shfl_xor(s0, s);
            s1 += __shfl_xor(s1, s);
        }
        float inv0 = 1.0f / (s0 + 1e-16f), inv1 = 1.0f / (s1 + 1e-16f);
        for (int i = 0; i < deg; i++) {
            float4 c = csr4[start + i];
            int sidx = __float_as_int(c.x);
            float al0 = __expf(c.y - m0) * inv0;
            float al1 = __expf(c.z - m1) * inv1;
            float alpha = (lane < 32) ? al0 : al1;
            unsigned u = *(const unsigned*)(xl + (size_t)sidx * 128 + lane * 2);
            float g0 = bfl(u) * alpha, g1 = bfh(u) * alpha;
            sum0 += g0; sum1 += g1;
            sq0 += g0 * g0; sq1 += g1 * g1;
            mn0 = fminf(mn0, g0); mn1 = fminf(mn1, g1);
            mx0 = fmaxf(mx0, g0); mx1 = fmaxf(mx1, g1);
        }
    } else {
        mn0 = mn1 = mx0 = mx1 = 0.f;
    }

    float cc = deg > 0 ? (float)deg : 1.0f;
    float mean0 = sum0 / cc, mean1 = sum1 / cc;
    float sd0 = sqrtf(fmaxf(sq0 / cc - mean0 * mean0, 0.0f) + 1e-5f);
    float sd1 = sqrtf(fmaxf(sq1 / cc - mean1 * mean1, 0.0f) + 1e-5f);

    int c2 = lane * 2, h = c2 >> 6, c = c2 & 63;
    unsigned short* ob = out_ws + (size_t)n * 512 + h * 256 + c;
    *(unsigned*)(ob + 0)   = pack2(mean0, mean1);
    *(unsigned*)(ob + 64)  = pack2(mn0, mn1);
    *(unsigned*)(ob + 128) = pack2(mx0, mx1);
    *(unsigned*)(ob + 192) = pack2(sd0, sd1);
}

// ---------------- K5: MFMA bf16 GEMM  out[64n x 128c] = A[64][512] @ W[512][128]
__global__ __launch_bounds__(256) void k_proj3(const unsigned short* __restrict__ Abf,
                                               const unsigned short* __restrict__ WT,
                                               const float* __restrict__ bno,
                                               const int* __restrict__ counts,
                                               const float* __restrict__ avgsum,
                                               float* __restrict__ nout) {
    __shared__ unsigned short sA[64][40];
    __shared__ unsigned short sB[128][40];
    int t = threadIdx.x;
    int lane = t & 63, wave = t >> 6;
    int l15 = lane & 15, lq = lane >> 4;
    int n0 = blockIdx.x * 64;

    f32x4 acc[8];
    #pragma unroll
    for (int cb = 0; cb < 8; cb++) acc[cb] = (f32x4){0.f, 0.f, 0.f, 0.f};

    int arow = t >> 2, achk = (t & 3) * 8;
    int an = n0 + arow; if (an >= NN) an = NN - 1;
    const unsigned short* Aptr = Abf + (size_t)an * 512 + achk;
    int bcol0 = t >> 2,          bchk0 = (t & 3) * 8;
    int bcol1 = (t + 256) >> 2,  bchk1 = (t & 3) * 8;
    const unsigned short* Bptr0 = WT + (size_t)bcol0 * 512 + bchk0;
    const unsigned short* Bptr1 = WT + (size_t)bcol1 * 512 + bchk1;

    for (int kc = 0; kc < 512; kc += 32) {
        __syncthreads();
        *(uint4*)&sA[arow][achk]   = *(const uint4*)(Aptr + kc);
        *(uint4*)&sB[bcol0][bchk0] = *(const uint4*)(Bptr0 + kc);
        *(uint4*)&sB[bcol1][bchk1] = *(const uint4*)(Bptr1 + kc);
        __syncthreads();
        bf16x8 afrag = *(const bf16x8*)&sA[wave * 16 + l15][lq * 8];
        #pragma unroll
        for (int cb = 0; cb < 8; cb++) {
            bf16x8 bfrag = *(const bf16x8*)&sB[cb * 16 + l15][lq * 8];
            acc[cb] = __builtin_amdgcn_mfma_f32_16x16x32_bf16(afrag, bfrag, acc[cb], 0, 0, 0);
        }
    }

    float avg_log = *avgsum / (float)NN;
    int nodebase = n0 + wave * 16 + lq * 4;
    float s1v[4];
    #pragma unroll
    for (int r = 0; r < 4; r++) {
        int node = nodebase + r; if (node >= NN) node = NN - 1;
        float cnt = (float)counts[node];
        float ld = logf(fmaxf(cnt, 1.0f) + 1.0f);
        s1v[r] = ld / avg_log;
    }
    #pragma unroll
    for (int cb = 0; cb < 4; cb++) {
        int o = cb * 16 + l15;
        float bv = bno[o];
        #pragma unroll
        for (int r = 0; r < 4; r++) {
            int node = nodebase + r;
            if (node < NN)
                nout[(size_t)node * 64 + o] = acc[cb][r] + s1v[r] * acc[cb + 4][r] + bv;
        }
    }
}

extern "C" void kernel_launch(void* const* d_in, const int* in_sizes, int n_in,
                              void* d_out, int out_size, void* d_ws, size_t ws_size,
                              hipStream_t stream) {
    const float* x         = (const float*)d_in[0];
    const float* edge_attr = (const float*)d_in[1];
    const int*   ei        = (const int*)d_in[2];
    const float* W_l       = (const float*)d_in[3];
    const float* b_l       = (const float*)d_in[4];
    const float* W_e       = (const float*)d_in[5];
    const float* b_e       = (const float*)d_in[6];
    const float* att       = (const float*)d_in[7];
    const float* W_no      = (const float*)d_in[8];
    const float* b_no      = (const float*)d_in[9];
    const float* W_eo      = (const float*)d_in[10];
    const float* b_eo      = (const float*)d_in[11];

    float* nout = (float*)d_out;                    // [N, 64]
    float* eout = (float*)d_out + (size_t)NN * 64;  // [E, 32]

    char* ws = (char*)d_ws;
    size_t off = 0;
    auto take = [&](size_t bytes) -> char* {
        char* p = ws + off;
        off = (off + bytes + 255) & ~(size_t)255;
        return p;
    };
    unsigned short* xl = (unsigned short*)take((size_t)NN * 128 * 2);
    float* ai        = (float*)take((size_t)NN * 2 * 4);
    float* aj        = (float*)take((size_t)NN * 2 * 4);
    float4* csr4     = (float4*)take((size_t)EE * 16);
    int*   rank      = (int*)take((size_t)EE * 4);
    int*   counts    = (int*)take((size_t)NN * 4);
    int*   offsets   = (int*)take((size_t)NN * 4);
    int*   bsums     = (int*)take(256 * 4);
    float* Wc        = (float*)take(32 * 32 * 4);
    float* bc        = (float*)take(32 * 4);
    unsigned short* WlT    = (unsigned short*)take((size_t)128 * 128 * 2);
    unsigned short* WT     = (unsigned short*)take((size_t)128 * 512 * 2);
    float* avgsum    = (float*)take(4);
    unsigned short* out_ws = (unsigned short*)take((size_t)NN * 512 * 2);

    hipMemsetAsync(counts, 0, (size_t)NN * 4, stream);
    hipMemsetAsync(avgsum, 0, 4, stream);

    k_prep<<<130, 512, 0, stream>>>(W_e, b_e, W_eo, b_eo, W_l, W_no, Wc, bc, WlT, WT);
    k_node3<<<NODE_BLOCKS + COUNT_BLOCKS, 256, 0, stream>>>(x, WlT, b_l, att, ei,
                                                            counts, rank, xl, ai, aj);
    int nb = (NN + 1023) / 1024;
    k_scan1<<<nb, 1024, 0, stream>>>(counts, offsets, bsums, avgsum);
    k_scan23<<<nb, 1024, 0, stream>>>(offsets, bsums);
    k_edge8<<<EE / 256, 256, 0, stream>>>(edge_attr, ei, W_e, b_e, att, Wc, bc,
                                          ai, aj, offsets, rank, csr4, eout);
    k_aggr2<<<(NN + 3) / 4, 256, 0, stream>>>(counts, offsets, csr4, xl, out_ws);
    k_proj3<<<(NN + 63) / 64, 256, 0, stream>>>(out_ws, WT, b_no, counts, avgsum, nout);
}

// Round 15
// 186.454 us; speedup vs baseline: 1.1807x; 1.1807x over previous
//
#include <hip/hip_runtime.h>
#include <hip/hip_bf16.h>

#define NN 50000
#define EE 800000
#define HH 2
#define CC 64
#define CEE 32
#define NODE_BLOCKS ((NN + 63) / 64)
#define COUNT_BLOCKS ((EE + 255) / 256)

typedef __attribute__((ext_vector_type(8))) short bf16x8;
typedef __attribute__((ext_vector_type(4))) float f32x4;

__device__ __forceinline__ short f2bf(float f) {
    union { float f; unsigned u; } v; v.f = f;
    unsigned r = v.u + 0x7FFF + ((v.u >> 16) & 1);   // RNE
    return (short)(r >> 16);
}
__device__ __forceinline__ unsigned pack2(float a, float b) {
    return (unsigned)(unsigned short)f2bf(a) | ((unsigned)(unsigned short)f2bf(b) << 16);
}
__device__ __forceinline__ float bfh(unsigned u) { return __uint_as_float(u & 0xFFFF0000u); }
__device__ __forceinline__ float bfl(unsigned u) { return __uint_as_float(u << 16); }

// ---------------- K_prep (fused): b0 = Wc/bc combine, b1 = WlT bf16 transpose,
// b2..129 = projection WT rows, b130..155 = zero counts/avgsum (replaces memsets)
__global__ __launch_bounds__(512) void k_prep(const float* __restrict__ We,
                                              const float* __restrict__ be,
                                              const float* __restrict__ Weo,
                                              const float* __restrict__ beo,
                                              const float* __restrict__ Wl,
                                              const float* __restrict__ Wno,
                                              float* __restrict__ Wc,
                                              float* __restrict__ bc,
                                              unsigned short* __restrict__ WlT,
                                              unsigned short* __restrict__ WT,
                                              int* __restrict__ counts,
                                              float* __restrict__ avgsum) {
    int b = blockIdx.x, t = threadIdx.x;
    if (b >= 130) {
        int base = (b - 130) * 2048 + t * 4;
        if (base < NN) {
            int4 z = make_int4(0, 0, 0, 0);
            if (base + 3 < NN) *(int4*)(counts + base) = z;
            else for (int q = 0; q < 4 && base + q < NN; q++) counts[base + q] = 0;
        }
        if (b == 130 && t == 0) *avgsum = 0.f;
        return;
    }
    if (b == 0) {
        for (int i = t; i < 1024; i += 512) {
            int r = i >> 5, j = i & 31;
            float s = 0.f;
            #pragma unroll
            for (int k = 0; k < 64; k++) s += We[r * 64 + k] * Weo[k * 32 + j];
            Wc[i] = s;
        }
        if (t < 32) {
            float bsum = beo[t];
            #pragma unroll
            for (int k = 0; k < 64; k++) bsum += be[k] * Weo[k * 32 + t];
            bc[t] = bsum;
        }
    } else if (b == 1) {
        for (int i = t; i < 16384; i += 512) {
            int o = i >> 7, k = i & 127;
            WlT[o * 128 + k] = (unsigned short)f2bf(Wl[k * 128 + o]);
        }
    } else {
        int o = b - 2;         // 0..127
        int r = t;             // 0..511  (= h*256 + agg*64 + c)
        int h = r >> 8, q = r & 255;
        const float* base = Wno + (size_t)(h * 768 + q) * 64;
        float v;
        if (o < 64) v = base[o] + base[512 * 64 + o];
        else        v = base[256 * 64 + (o - 64)];
        WT[(size_t)o * 512 + r] = (unsigned short)f2bf(v);
    }
}

// ---------------- K1: MFMA bf16 GEMM xl = x @ W_l + b_l; fused ai/aj epilogue.
// Extra blocks (>= NODE_BLOCKS) do the degree count + rank assignment.
__global__ __launch_bounds__(256) void k_node3(const float* __restrict__ x,
                                               const unsigned short* __restrict__ WlT,
                                               const float* __restrict__ bl,
                                               const float* __restrict__ att,
                                               const int* __restrict__ ei,
                                               int* __restrict__ counts,
                                               int* __restrict__ rank,
                                               unsigned short* __restrict__ xl,
                                               float* __restrict__ ai,
                                               float* __restrict__ aj) {
    if ((int)blockIdx.x >= NODE_BLOCKS) {
        int e = ((int)blockIdx.x - NODE_BLOCKS) * 256 + threadIdx.x;
        if (e < EE) rank[e] = atomicAdd(&counts[ei[EE + e]], 1);
        return;
    }
    __shared__ unsigned short sX[64][40];    // 64 nodes x 32-k chunk bf16
    __shared__ unsigned short sW[128][40];   // 128 out-cols x 32-k chunk bf16
    int t = threadIdx.x;
    int lane = t & 63, wave = t >> 6;
    int l15 = lane & 15, lq = lane >> 4;
    int n0 = blockIdx.x * 64;

    f32x4 acc[8];
    #pragma unroll
    for (int cb = 0; cb < 8; cb++) acc[cb] = (f32x4){0.f, 0.f, 0.f, 0.f};

    int arow = t >> 2, achk = (t & 3) * 8;
    int an = n0 + arow; if (an >= NN) an = NN - 1;
    const float* Aptr = x + (size_t)an * 128 + achk;
    int bcol0 = t >> 2, bcol1 = (t + 256) >> 2, bchk = (t & 3) * 8;
    const unsigned short* Bp0 = WlT + (size_t)bcol0 * 128 + bchk;
    const unsigned short* Bp1 = WlT + (size_t)bcol1 * 128 + bchk;

    for (int kc = 0; kc < 128; kc += 32) {
        __syncthreads();
        float4 a0 = *(const float4*)(Aptr + kc);
        float4 a1 = *(const float4*)(Aptr + kc + 4);
        uint4 pk;
        pk.x = pack2(a0.x, a0.y); pk.y = pack2(a0.z, a0.w);
        pk.z = pack2(a1.x, a1.y); pk.w = pack2(a1.z, a1.w);
        *(uint4*)&sX[arow][achk] = pk;
        *(uint4*)&sW[bcol0][bchk] = *(const uint4*)(Bp0 + kc);
        *(uint4*)&sW[bcol1][bchk] = *(const uint4*)(Bp1 + kc);
        __syncthreads();
        bf16x8 afrag = *(const bf16x8*)&sX[wave * 16 + l15][lq * 8];
        #pragma unroll
        for (int cb = 0; cb < 8; cb++) {
            bf16x8 bfrag = *(const bf16x8*)&sW[cb * 16 + l15][lq * 8];
            acc[cb] = __builtin_amdgcn_mfma_f32_16x16x32_bf16(afrag, bfrag, acc[cb], 0, 0, 0);
        }
    }

    // epilogue: +bias, bf16 xl write, lrelu*att partials, l15-butterfly
    float blv[8], atti[8], attj[8];
    #pragma unroll
    for (int cb = 0; cb < 8; cb++) {
        int o = cb * 16 + l15;
        blv[cb] = bl[o];
        int h = o >> 6, c = o & 63;
        atti[cb] = att[h * 160 + c];
        attj[cb] = att[h * 160 + 64 + c];
    }
    int nodebase = n0 + wave * 16 + lq * 4;
    #pragma unroll
    for (int r = 0; r < 4; r++) {
        int node = nodebase + r;
        bool ok = node < NN;
        float s0a = 0.f, s1a = 0.f, s0j = 0.f, s1j = 0.f;
        #pragma unroll
        for (int cb = 0; cb < 8; cb++) {
            float v = acc[cb][r] + blv[cb];
            if (ok) xl[(size_t)node * 128 + cb * 16 + l15] = (unsigned short)f2bf(v);
            float lr = v > 0.f ? v : 0.2f * v;
            if (cb < 4) { s0a += lr * atti[cb]; s0j += lr * attj[cb]; }
            else        { s1a += lr * atti[cb]; s1j += lr * attj[cb]; }
        }
        #pragma unroll
        for (int m = 1; m <= 8; m <<= 1) {
            s0a += __shfl_xor(s0a, m); s1a += __shfl_xor(s1a, m);
            s0j += __shfl_xor(s0j, m); s1j += __shfl_xor(s1j, m);
        }
        if (l15 == 0 && ok) {
            *(float2*)(ai + (size_t)node * 2) = make_float2(s0a, s1a);
            *(float2*)(aj + (size_t)node * 2) = make_float2(s0j, s1j);
        }
    }
}

// ---------------- scan: block-local exclusive + bsums + avg_log
__global__ __launch_bounds__(1024) void k_scan1(const int* __restrict__ counts,
                                                int* __restrict__ offsets,
                                                int* __restrict__ bsums,
                                                float* __restrict__ avgsum) {
    __shared__ int s[1024];
    int g = blockIdx.x * 1024 + threadIdx.x;
    int v = (g < NN) ? counts[g] : 0;
    s[threadIdx.x] = v;
    __syncthreads();
    for (int st = 1; st < 1024; st <<= 1) {
        int t = (threadIdx.x >= st) ? s[threadIdx.x - st] : 0;
        __syncthreads();
        s[threadIdx.x] += t;
        __syncthreads();
    }
    if (g < NN) offsets[g] = s[threadIdx.x] - v;
    if (threadIdx.x == 1023) bsums[blockIdx.x] = s[1023];
    float lv = (g < NN) ? logf((float)v + 1.0f) : 0.0f;
    #pragma unroll
    for (int m = 32; m; m >>= 1) lv += __shfl_xor(lv, m);
    if ((threadIdx.x & 63) == 0) atomicAdd(avgsum, lv);
}

// scan2+scan3 fused: block base = sum(bsums[0..bid-1]) computed in-wave (nb<=64)
__global__ __launch_bounds__(1024) void k_scan23(int* __restrict__ offsets,
                                                 const int* __restrict__ bsums) {
    __shared__ int sbase;
    int t = threadIdx.x;
    if (t < 64) {
        int v = (t < (int)blockIdx.x) ? bsums[t] : 0;
        #pragma unroll
        for (int m = 32; m; m >>= 1) v += __shfl_xor(v, m);
        if (t == 0) sbase = v;
    }
    __syncthreads();
    int g = blockIdx.x * 1024 + t;
    if (g < NN) offsets[g] += sbase;
}

// ---------------- K3: MFMA edge pass (round-12 k_edge7 structure; register
// constants — LDS-constants variant regressed). eout stores non-temporal.
__global__ __launch_bounds__(256) void k_edge7(const float* __restrict__ ea,
                                               const int* __restrict__ ei,
                                               const float* __restrict__ We,
                                               const float* __restrict__ be,
                                               const float* __restrict__ att,
                                               const float* __restrict__ Wc,
                                               const float* __restrict__ bc,
                                               const float* __restrict__ ai,
                                               const float* __restrict__ aj,
                                               const int* __restrict__ offsets,
                                               const int* __restrict__ rank,
                                               float4* __restrict__ csr4,
                                               float* __restrict__ eout) {
    int t = threadIdx.x;
    int lane = t & 63, wave = t >> 6;
    int l15 = lane & 15, lq = lane >> 4;
    int ew0 = blockIdx.x * 256 + wave * 64;

    // metadata first (longest dependent chain: dst -> offsets/ai)
    int myE = ew0 + lane;
    int msrc = ei[myE], mdst = ei[EE + myE];
    int myrank = rank[myE];
    int obase = offsets[mdst];
    float2 aiv = *(const float2*)(ai + (size_t)mdst * 2);
    float2 ajv = *(const float2*)(aj + (size_t)msrc * 2);

    // attr loads: 2-deep double buffer, convert to bf16 immediately
    bf16x8 bEall[4];
    {
        float4 fb0, fb1;
        {
            const float4* p = (const float4*)(ea + (size_t)(ew0 + l15) * 32 + lq * 8);
            fb0 = p[0]; fb1 = p[1];
        }
        #pragma unroll
        for (int g = 0; g < 4; g++) {
            float4 c0 = fb0, c1 = fb1;
            if (g < 3) {
                const float4* p = (const float4*)(ea + (size_t)(ew0 + (g + 1) * 16 + l15) * 32 + lq * 8);
                fb0 = p[0]; fb1 = p[1];
            }
            bf16x8 bE;
            bE[0] = f2bf(c0.x); bE[1] = f2bf(c0.y); bE[2] = f2bf(c0.z); bE[3] = f2bf(c0.w);
            bE[4] = f2bf(c1.x); bE[5] = f2bf(c1.y); bE[6] = f2bf(c1.z); bE[7] = f2bf(c1.w);
            bEall[g] = bE;
        }
    }

    bf16x8 aWe[4], aWc[2];
    #pragma unroll
    for (int mb = 0; mb < 4; mb++)
        #pragma unroll
        for (int j = 0; j < 8; j++)
            aWe[mb][j] = f2bf(We[(lq * 8 + j) * 64 + mb * 16 + l15]);
    #pragma unroll
    for (int cb = 0; cb < 2; cb++)
        #pragma unroll
        for (int j = 0; j < 8; j++)
            aWc[cb][j] = f2bf(Wc[(lq * 8 + j) * 32 + cb * 16 + l15]);

    f32x4 beC[4], bcC[2];
    float attR[4][4];
    #pragma unroll
    for (int mb = 0; mb < 4; mb++)
        #pragma unroll
        for (int r = 0; r < 4; r++) {
            int m = mb * 16 + lq * 4 + r;
            beC[mb][r] = be[m];
            attR[mb][r] = att[(m >> 5) * 160 + 128 + (m & 31)];
        }
    #pragma unroll
    for (int cb = 0; cb < 2; cb++)
        #pragma unroll
        for (int r = 0; r < 4; r++)
            bcC[cb][r] = bc[cb * 16 + lq * 4 + r];

    float myP0 = 0.f, myP1 = 0.f;

    #pragma unroll
    for (int g = 0; g < 4; g++) {
        int e = ew0 + g * 16 + l15;
        bf16x8 bE = bEall[g];

        float p0 = 0.f, p1 = 0.f;
        #pragma unroll
        for (int mb = 0; mb < 4; mb++) {
            f32x4 acc = __builtin_amdgcn_mfma_f32_16x16x32_bf16(aWe[mb], bE, beC[mb], 0, 0, 0);
            float ps = 0.f;
            #pragma unroll
            for (int r = 0; r < 4; r++) {
                float m = acc[r];
                float lr = m > 0.f ? m : 0.2f * m;
                ps += lr * attR[mb][r];
            }
            if (mb < 2) p0 += ps; else p1 += ps;
        }
        p0 += __shfl_xor(p0, 16); p0 += __shfl_xor(p0, 32);
        p1 += __shfl_xor(p1, 16); p1 += __shfl_xor(p1, 32);
        if (lq == g) { myP0 = p0; myP1 = p1; }

        #pragma unroll
        for (int cb = 0; cb < 2; cb++) {
            f32x4 oc = __builtin_amdgcn_mfma_f32_16x16x32_bf16(aWc[cb], bE, bcC[cb], 0, 0, 0);
            __builtin_nontemporal_store(oc, (f32x4*)(eout + (size_t)e * 32 + cb * 16 + lq * 4));
        }
    }

    float lg0 = myP0 + aiv.x + ajv.x;
    float lg1 = myP1 + aiv.y + ajv.y;
    csr4[obase + myrank] = make_float4(__int_as_float(msrc), lg0, lg1, 0.f);
}

// ---------------- K4: one wave per NODE, both heads fused; LDS-broadcast alphas
__global__ __launch_bounds__(256) void k_aggr2(const int* __restrict__ counts,
                                               const int* __restrict__ offsets,
                                               const float4* __restrict__ csr4,
                                               const unsigned short* __restrict__ xl,
                                               unsigned short* __restrict__ out_ws) {
    __shared__ float4 sal[4][64];   // per-wave {src, a0, a1, -} table (4 KB)
    int lane = threadIdx.x & 63;
    int wv = threadIdx.x >> 6;
    int n = blockIdx.x * 4 + wv;
    if (n >= NN) return;
    int deg = counts[n], start = offsets[n];

    float sum0 = 0.f, sum1 = 0.f, sq0 = 0.f, sq1 = 0.f;
    float mn0 = 1e30f, mn1 = 1e30f, mx0 = -1e30f, mx1 = -1e30f;

    if (deg > 0 && deg <= 64) {
        float2 lg = make_float2(-1e30f, -1e30f);
        int srcv = 0;
        if (lane < deg) {
            float4 c = csr4[start + lane];
            srcv = __float_as_int(c.x);
            lg = make_float2(c.y, c.z);
        }
        float m0 = lg.x, m1 = lg.y;
        #pragma unroll
        for (int s = 32; s; s >>= 1) {
            m0 = fmaxf(m0, __shfl_xor(m0, s));
            m1 = fmaxf(m1, __shfl_xor(m1, s));
        }
        float e0 = (lane < deg) ? __expf(lg.x - m0) : 0.f;
        float e1 = (lane < deg) ? __expf(lg.y - m1) : 0.f;
        float s0 = e0, s1 = e1;
        #pragma unroll
        for (int s = 32; s; s >>= 1) {
            s0 += __shfl_xor(s0, s);
            s1 += __shfl_xor(s1, s);
        }
        sal[wv][lane] = make_float4(__int_as_float(srcv),
                                    e0 / (s0 + 1e-16f), e1 / (s1 + 1e-16f), 0.f);
        #pragma unroll 4
        for (int i = 0; i < deg; i++) {
            float4 c = sal[wv][i];                 // broadcast read, conflict-free
            int sidx = __float_as_int(c.x);
            float alpha = (lane < 32) ? c.y : c.z;
            unsigned u = *(const unsigned*)(xl + (size_t)sidx * 128 + lane * 2);
            float g0 = bfl(u) * alpha, g1 = bfh(u) * alpha;
            sum0 += g0; sum1 += g1;
            sq0 += g0 * g0; sq1 += g1 * g1;
            mn0 = fminf(mn0, g0); mn1 = fminf(mn1, g1);
            mx0 = fmaxf(mx0, g0); mx1 = fmaxf(mx1, g1);
        }
    } else if (deg > 64) {
        float m0 = -1e30f, m1 = -1e30f;
        for (int i = lane; i < deg; i += 64) {
            float4 c = csr4[start + i];
            m0 = fmaxf(m0, c.y); m1 = fmaxf(m1, c.z);
        }
        #pragma unroll
        for (int s = 32; s; s >>= 1) {
            m0 = fmaxf(m0, __shfl_xor(m0, s));
            m1 = fmaxf(m1, __shfl_xor(m1, s));
        }
        float s0 = 0.f, s1 = 0.f;
        for (int i = lane; i < deg; i += 64) {
            float4 c = csr4[start + i];
            s0 += __expf(c.y - m0); s1 += __expf(c.z - m1);
        }
        #pragma unroll
        for (int s = 32; s; s >>= 1) {
            s0 += __shfl_xor(s0, s);
            s1 += __shfl_xor(s1, s);
        }
        float inv0 = 1.0f / (s0 + 1e-16f), inv1 = 1.0f / (s1 + 1e-16f);
        for (int i = 0; i < deg; i++) {
            float4 c = csr4[start + i];
            int sidx = __float_as_int(c.x);
            float al0 = __expf(c.y - m0) * inv0;
            float al1 = __expf(c.z - m1) * inv1;
            float alpha = (lane < 32) ? al0 : al1;
            unsigned u = *(const unsigned*)(xl + (size_t)sidx * 128 + lane * 2);
            float g0 = bfl(u) * alpha, g1 = bfh(u) * alpha;
            sum0 += g0; sum1 += g1;
            sq0 += g0 * g0; sq1 += g1 * g1;
            mn0 = fminf(mn0, g0); mn1 = fminf(mn1, g1);
            mx0 = fmaxf(mx0, g0); mx1 = fmaxf(mx1, g1);
        }
    } else {
        mn0 = mn1 = mx0 = mx1 = 0.f;
    }

    float cc = deg > 0 ? (float)deg : 1.0f;
    float mean0 = sum0 / cc, mean1 = sum1 / cc;
    float sd0 = sqrtf(fmaxf(sq0 / cc - mean0 * mean0, 0.0f) + 1e-5f);
    float sd1 = sqrtf(fmaxf(sq1 / cc - mean1 * mean1, 0.0f) + 1e-5f);

    int c2 = lane * 2, h = c2 >> 6, c = c2 & 63;
    unsigned short* ob = out_ws + (size_t)n * 512 + h * 256 + c;
    *(unsigned*)(ob + 0)   = pack2(mean0, mean1);
    *(unsigned*)(ob + 64)  = pack2(mn0, mn1);
    *(unsigned*)(ob + 128) = pack2(mx0, mx1);
    *(unsigned*)(ob + 192) = pack2(sd0, sd1);
}

// ---------------- K5: MFMA bf16 GEMM  out[64n x 128c] = A[64][512] @ W[512][128]
__global__ __launch_bounds__(256) void k_proj3(const unsigned short* __restrict__ Abf,
                                               const unsigned short* __restrict__ WT,
                                               const float* __restrict__ bno,
                                               const int* __restrict__ counts,
                                               const float* __restrict__ avgsum,
                                               float* __restrict__ nout) {
    __shared__ unsigned short sA[64][40];
    __shared__ unsigned short sB[128][40];
    int t = threadIdx.x;
    int lane = t & 63, wave = t >> 6;
    int l15 = lane & 15, lq = lane >> 4;
    int n0 = blockIdx.x * 64;

    f32x4 acc[8];
    #pragma unroll
    for (int cb = 0; cb < 8; cb++) acc[cb] = (f32x4){0.f, 0.f, 0.f, 0.f};

    int arow = t >> 2, achk = (t & 3) * 8;
    int an = n0 + arow; if (an >= NN) an = NN - 1;
    const unsigned short* Aptr = Abf + (size_t)an * 512 + achk;
    int bcol0 = t >> 2,          bchk0 = (t & 3) * 8;
    int bcol1 = (t + 256) >> 2,  bchk1 = (t & 3) * 8;
    const unsigned short* Bptr0 = WT + (size_t)bcol0 * 512 + bchk0;
    const unsigned short* Bptr1 = WT + (size_t)bcol1 * 512 + bchk1;

    for (int kc = 0; kc < 512; kc += 32) {
        __syncthreads();
        *(uint4*)&sA[arow][achk]   = *(const uint4*)(Aptr + kc);
        *(uint4*)&sB[bcol0][bchk0] = *(const uint4*)(Bptr0 + kc);
        *(uint4*)&sB[bcol1][bchk1] = *(const uint4*)(Bptr1 + kc);
        __syncthreads();
        bf16x8 afrag = *(const bf16x8*)&sA[wave * 16 + l15][lq * 8];
        #pragma unroll
        for (int cb = 0; cb < 8; cb++) {
            bf16x8 bfrag = *(const bf16x8*)&sB[cb * 16 + l15][lq * 8];
            acc[cb] = __builtin_amdgcn_mfma_f32_16x16x32_bf16(afrag, bfrag, acc[cb], 0, 0, 0);
        }
    }

    float avg_log = *avgsum / (float)NN;
    int nodebase = n0 + wave * 16 + lq * 4;
    float s1v[4];
    #pragma unroll
    for (int r = 0; r < 4; r++) {
        int node = nodebase + r; if (node >= NN) node = NN - 1;
        float cnt = (float)counts[node];
        float ld = logf(fmaxf(cnt, 1.0f) + 1.0f);
        s1v[r] = ld / avg_log;
    }
    #pragma unroll
    for (int cb = 0; cb < 4; cb++) {
        int o = cb * 16 + l15;
        float bv = bno[o];
        #pragma unroll
        for (int r = 0; r < 4; r++) {
            int node = nodebase + r;
            if (node < NN)
                nout[(size_t)node * 64 + o] = acc[cb][r] + s1v[r] * acc[cb + 4][r] + bv;
        }
    }
}

extern "C" void kernel_launch(void* const* d_in, const int* in_sizes, int n_in,
                              void* d_out, int out_size, void* d_ws, size_t ws_size,
                              hipStream_t stream) {
    const float* x         = (const float*)d_in[0];
    const float* edge_attr = (const float*)d_in[1];
    const int*   ei        = (const int*)d_in[2];
    const float* W_l       = (const float*)d_in[3];
    const float* b_l       = (const float*)d_in[4];
    const float* W_e       = (const float*)d_in[5];
    const float* b_e       = (const float*)d_in[6];
    const float* att       = (const float*)d_in[7];
    const float* W_no      = (const float*)d_in[8];
    const float* b_no      = (const float*)d_in[9];
    const float* W_eo      = (const float*)d_in[10];
    const float* b_eo      = (const float*)d_in[11];

    float* nout = (float*)d_out;                    // [N, 64]
    float* eout = (float*)d_out + (size_t)NN * 64;  // [E, 32]

    char* ws = (char*)d_ws;
    size_t off = 0;
    auto take = [&](size_t bytes) -> char* {
        char* p = ws + off;
        off = (off + bytes + 255) & ~(size_t)255;
        return p;
    };
    unsigned short* xl = (unsigned short*)take((size_t)NN * 128 * 2);
    float* ai        = (float*)take((size_t)NN * 2 * 4);
    float* aj        = (float*)take((size_t)NN * 2 * 4);
    float4* csr4     = (float4*)take((size_t)EE * 16);
    int*   rank      = (int*)take((size_t)EE * 4);
    int*   counts    = (int*)take((size_t)NN * 4);
    int*   offsets   = (int*)take((size_t)NN * 4);
    int*   bsums     = (int*)take(256 * 4);
    float* Wc        = (float*)take(32 * 32 * 4);
    float* bc        = (float*)take(32 * 4);
    unsigned short* WlT    = (unsigned short*)take((size_t)128 * 128 * 2);
    unsigned short* WT     = (unsigned short*)take((size_t)128 * 512 * 2);
    float* avgsum    = (float*)take(4);
    unsigned short* out_ws = (unsigned short*)take((size_t)NN * 512 * 2);

    k_prep<<<130 + 25, 512, 0, stream>>>(W_e, b_e, W_eo, b_eo, W_l, W_no,
                                         Wc, bc, WlT, WT, counts, avgsum);
    k_node3<<<NODE_BLOCKS + COUNT_BLOCKS, 256, 0, stream>>>(x, WlT, b_l, att, ei,
                                                            counts, rank, xl, ai, aj);
    int nb = (NN + 1023) / 1024;
    k_scan1<<<nb, 1024, 0, stream>>>(counts, offsets, bsums, avgsum);
    k_scan23<<<nb, 1024, 0, stream>>>(offsets, bsums);
    k_edge7<<<EE / 256, 256, 0, stream>>>(edge_attr, ei, W_e, b_e, att, Wc, bc,
                                          ai, aj, offsets, rank, csr4, eout);
    k_aggr2<<<(NN + 3) / 4, 256, 0, stream>>>(counts, offsets, csr4, xl, out_ws);
    k_proj3<<<(NN + 63) / 64, 256, 0, stream>>>(out_ws, WT, b_no, counts, avgsum, nout);
}